// Round 8
// baseline (279.777 us; speedup 1.0000x reference)
//
#include <hip/hip_runtime.h>
#include <hip/hip_bf16.h>

typedef __bf16 bf16x8 __attribute__((ext_vector_type(8)));
typedef __bf16 bf16x4 __attribute__((ext_vector_type(4)));
typedef float f32x4 __attribute__((ext_vector_type(4)));

#define NB 4
#define NS 2048
#define ND 1024
#define NH 16
#define NDH 64
#define NM (NB*NS)   // 8192

#define MFMA(a,b,c) __builtin_amdgcn_mfma_f32_16x16x32_bf16((a),(b),(c),0,0,0)

__device__ __forceinline__ void gload16(const void* g, void* l) {
    __builtin_amdgcn_global_load_lds(
        (const __attribute__((address_space(1))) void*)(g),
        (__attribute__((address_space(3))) void*)(l),
        16, 0, 0);
}

// ---------------- cast fp32 -> bf16, vectorized ----------------
__global__ __launch_bounds__(256) void cast4(const float* __restrict__ in,
                                             __bf16* __restrict__ out, int n) {
    int i = (blockIdx.x * 256 + threadIdx.x) * 4;
    if (i >= n) return;
    float4 v = *(const float4*)(in + i);
    bf16x4 o;
    o[0] = (__bf16)v.x; o[1] = (__bf16)v.y; o[2] = (__bf16)v.z; o[3] = (__bf16)v.w;
    *(bf16x4*)(out + i) = o;
}

// ---------------- 128x128 GEMM, A[M,K] * W[N,K]^T ----------------
// MODE 0: z=0 -> Q [B,H,S,Dh] (scaled by 1/8*log2e), z=1 -> K, z=2 -> V^T [B,H,Dh,S]
// MODE 1: C fp32 row-major [M,N]
template<int MODE>
__global__ __launch_bounds__(256) void gemm128(
    const __bf16* __restrict__ A,
    const __bf16* __restrict__ W0, const __bf16* __restrict__ W1,
    const __bf16* __restrict__ W2,
    __bf16* __restrict__ O0, __bf16* __restrict__ O1, __bf16* __restrict__ O2,
    float* __restrict__ Cf)
{
    __shared__ alignas(16) __bf16 As[128*32];
    __shared__ alignas(16) __bf16 Bs[128*32];

    const int tid  = threadIdx.x;
    const int wave = tid >> 6, lane = tid & 63;
    const int l16  = lane & 15, lq = lane >> 4;
    const int bm = blockIdx.x * 128;
    const int bn = blockIdx.y * 128;
    const int z  = (MODE == 0) ? blockIdx.z : 0;
    const __bf16* __restrict__ Bw =
        (MODE == 0) ? ((z == 0) ? W0 : (z == 1) ? W1 : W2) : W0;

    const int wr = (wave >> 1) * 64;
    const int wc = (wave & 1) * 64;

    f32x4 acc[4][4];
    #pragma unroll
    for (int i = 0; i < 4; i++)
        #pragma unroll
        for (int j = 0; j < 4; j++)
            acc[i][j] = (f32x4){0.f, 0.f, 0.f, 0.f};

    const int ch0 = tid, ch1 = tid + 256;
    const int r0 = ch0 >> 2, c0 = (ch0 & 3) * 8;
    const int r1 = ch1 >> 2, c1 = (ch1 & 3) * 8;

    for (int k0 = 0; k0 < ND; k0 += 32) {
        __syncthreads();
        gload16(A  + (size_t)(bm + r0) * ND + k0 + c0, As + ch0 * 8);
        gload16(Bw + (size_t)(bn + r0) * ND + k0 + c0, Bs + ch0 * 8);
        gload16(A  + (size_t)(bm + r1) * ND + k0 + c1, As + ch1 * 8);
        gload16(Bw + (size_t)(bn + r1) * ND + k0 + c1, Bs + ch1 * 8);
        __syncthreads();

        bf16x8 af[4], bf[4];
        #pragma unroll
        for (int i = 0; i < 4; i++) {
            af[i] = *(const bf16x8*)(As + (wr + i*16 + l16) * 32 + lq * 8);
            bf[i] = *(const bf16x8*)(Bs + (wc + i*16 + l16) * 32 + lq * 8);
        }
        #pragma unroll
        for (int i = 0; i < 4; i++)
            #pragma unroll
            for (int j = 0; j < 4; j++)
                acc[i][j] = MFMA(af[i], bf[j], acc[i][j]);
    }

    #pragma unroll
    for (int i = 0; i < 4; i++) {
        #pragma unroll
        for (int j = 0; j < 4; j++) {
            #pragma unroll
            for (int r = 0; r < 4; r++) {
                int row = bm + wr + i*16 + lq*4 + r;   // m index (b*S + s)
                int col = bn + wc + j*16 + l16;        // n index (d_out)
                float v = acc[i][j][r];
                if (MODE == 1) {
                    Cf[(size_t)row * ND + col] = v;
                } else {
                    if (z == 0) v *= 0.1803368801111204f;  // 1/8 * log2(e)
                    int b = row >> 11, s = row & 2047;
                    int h = col >> 6,  dh = col & 63;
                    if (z < 2) {
                        __bf16* dst = (z == 0) ? O0 : O1;
                        dst[(((size_t)b*NH + h)*NS + s)*NDH + dh] = (__bf16)v;
                    } else {
                        O2[(((size_t)b*NH + h)*NDH + dh)*NS + s] = (__bf16)v;
                    }
                }
            }
        }
    }
}

// ------- causal flash attention: split-KV, wave-independent inner loop -------
// Task = (bh, 32-row q-block j). Every task's kv range is SPLIT between two
// waves of the same block (flash-decoding): h0 = tiles [0,sp), h1 = [sp,ntk).
// Block = 4 waves = 2 tasks x 2 halves; tasks paired {63-p, p} so per-block
// work is ~constant. Critical path per wave: <=16 kv tiles (was 32).
// Partials merged through LDS with one __syncthreads.
// K/V fragments read straight from global (L2-resident). Q pre-scaled by
// 1/8*log2(e); scores in log2 units; defer-max online softmax.
__global__ __launch_bounds__(256, 2) void attn_wv(
    const __bf16* __restrict__ Q, const __bf16* __restrict__ K,
    const __bf16* __restrict__ Vt, __bf16* __restrict__ Oa)
{
    __shared__ alignas(16) __bf16 Ps[4][32*64];   // per-wave private 4 KB
    __shared__ float LO[2][32][68];               // partner O partials (padded)
    __shared__ float LM[2][32], LL[2][32];        // partner m, l per row

    const int tid  = threadIdx.x;
    const int wave = tid >> 6, lane = tid & 63;
    const int l16  = lane & 15, lq = lane >> 4;

    const int bid  = blockIdx.x;                  // 0..2047
    const int bh   = (bid & 7) * 8 + ((bid >> 3) & 7);  // head group pinned/XCD
    const int p    = bid >> 6;                    // 0..31
    const int pair = wave >> 1;                   // which task in the block
    const int hh   = wave & 1;                    // which kv half
    const int j    = pair ? p : 63 - p;           // q-block index 0..63
    const int q0   = j * 32;
    const int ntk  = (j >> 1) + 1;                // total kv tiles for task
    const int sp   = (ntk + 1) >> 1;              // split point
    const int tA   = hh ? sp : 0;
    const int tB   = hh ? ntk : sp;

    const int b = bh >> 4, h = bh & 15;
    const size_t qkb = (size_t)bh * NS * NDH;     // Q,K  [bh][s][dh]
    const size_t vbb = (size_t)bh * NDH * NS;     // Vt   [bh][dh][s]
    const int xs = (l16 & 7) << 3;
    __bf16* Pw = Ps[wave];

    // Q fragments (2 row-tiles x 2 k-chunks)
    bf16x8 qf[2][2];
    #pragma unroll
    for (int qi = 0; qi < 2; qi++) {
        const __bf16* qr = Q + qkb + (size_t)(q0 + qi*16 + l16) * NDH;
        qf[qi][0] = *(const bf16x8*)(qr + lq * 8);
        qf[qi][1] = *(const bf16x8*)(qr + 32 + lq * 8);
    }

    f32x4 o[2][4];
    float mr[2][4], ls[2][4];
    #pragma unroll
    for (int qi = 0; qi < 2; qi++)
        #pragma unroll
        for (int d = 0; d < 4; d++) {
            o[qi][d] = (f32x4){0.f, 0.f, 0.f, 0.f};
            mr[qi][d] = -__builtin_inff(); ls[qi][d] = 0.f;
        }

    #pragma unroll 1
    for (int t = tA; t < tB; ++t) {
        const int kv0 = t * 64;

        // K fragments straight from global (A-frag: l16 = kv row)
        bf16x8 kf[4][2];
        #pragma unroll
        for (int ni = 0; ni < 4; ni++) {
            const __bf16* kp = K + qkb + (size_t)(kv0 + ni*16 + l16) * NDH;
            kf[ni][0] = *(const bf16x8*)(kp + lq * 8);
            kf[ni][1] = *(const bf16x8*)(kp + 32 + lq * 8);
        }
        // V fragments straight from global (B-frag: l16 = d row)
        bf16x8 vb[4][2];
        #pragma unroll
        for (int d = 0; d < 4; d++) {
            const __bf16* vp = Vt + vbb + (size_t)(d*16 + l16) * NS + kv0;
            vb[d][0] = *(const bf16x8*)(vp + lq * 8);
            vb[d][1] = *(const bf16x8*)(vp + 32 + lq * 8);
        }

        const bool diag = (t == ntk - 1);

        #pragma unroll
        for (int qi = 0; qi < 2; qi++) {
            f32x4 s[4];
            __builtin_amdgcn_s_setprio(1);
            #pragma unroll
            for (int ni = 0; ni < 4; ni++) {
                f32x4 z = (f32x4){0.f, 0.f, 0.f, 0.f};
                z = MFMA(qf[qi][0], kf[ni][0], z);
                z = MFMA(qf[qi][1], kf[ni][1], z);
                s[ni] = z;
            }
            __builtin_amdgcn_s_setprio(0);

            if (diag) {
                #pragma unroll
                for (int ni = 0; ni < 4; ni++)
                    #pragma unroll
                    for (int r = 0; r < 4; r++) {
                        int col = kv0 + ni*16 + l16;
                        int row = q0 + qi*16 + lq*4 + r;
                        if (col > row) s[ni][r] = -__builtin_inff();
                    }
            }

            // row maxes (row q = lq*4+r, spread over l16 lanes)
            float pm[4];
            #pragma unroll
            for (int r = 0; r < 4; r++) {
                float tm = fmaxf(fmaxf(s[0][r], s[1][r]), fmaxf(s[2][r], s[3][r]));
                tm = fmaxf(tm, __shfl_xor(tm, 1));
                tm = fmaxf(tm, __shfl_xor(tm, 2));
                tm = fmaxf(tm, __shfl_xor(tm, 4));
                tm = fmaxf(tm, __shfl_xor(tm, 8));
                pm[r] = tm;
            }
            bool need = (pm[0] > mr[qi][0] + 8.f) | (pm[1] > mr[qi][1] + 8.f) |
                        (pm[2] > mr[qi][2] + 8.f) | (pm[3] > mr[qi][3] + 8.f);
            if (__any(need)) {
                #pragma unroll
                for (int r = 0; r < 4; r++) {
                    float mnew = fmaxf(mr[qi][r], pm[r]);
                    float fac = exp2f(mr[qi][r] - mnew);
                    mr[qi][r] = mnew;
                    ls[qi][r] *= fac;
                    #pragma unroll
                    for (int d = 0; d < 4; d++) o[qi][d][r] *= fac;
                }
            }
            #pragma unroll
            for (int r = 0; r < 4; r++) {
                const int prow = qi*16 + lq*4 + r;
                __bf16* pp = Pw + prow * 64;
                const int pxs = (prow & 7) << 3;
                float psum = 0.f;
                #pragma unroll
                for (int ni = 0; ni < 4; ni++) {
                    float pv = exp2f(s[ni][r] - mr[qi][r]);
                    pp[(ni*16 + l16) ^ pxs] = (__bf16)pv;
                    psum += pv;
                }
                ls[qi][r] += psum;
            }
        }

        // P relayout (wave-private; compiler inserts the lgkmcnt)
        bf16x8 pa[2][2];
        #pragma unroll
        for (int qi = 0; qi < 2; qi++) {
            const __bf16* pp = Pw + (qi*16 + l16) * 64;
            pa[qi][0] = *(const bf16x8*)(pp + ((lq*8) ^ xs));
            pa[qi][1] = *(const bf16x8*)(pp + ((32 + lq*8) ^ xs));
        }
        __builtin_amdgcn_s_setprio(1);
        #pragma unroll
        for (int d = 0; d < 4; d++)
            #pragma unroll
            for (int qi = 0; qi < 2; qi++) {
                o[qi][d] = MFMA(pa[qi][0], vb[d][0], o[qi][d]);
                o[qi][d] = MFMA(pa[qi][1], vb[d][1], o[qi][d]);
            }
        __builtin_amdgcn_s_setprio(0);
    }

    // complete per-row sums (partials were spread over l16 lanes)
    #pragma unroll
    for (int qi = 0; qi < 2; qi++)
        #pragma unroll
        for (int r = 0; r < 4; r++) {
            float t = ls[qi][r];
            t += __shfl_xor(t, 1); t += __shfl_xor(t, 2);
            t += __shfl_xor(t, 4); t += __shfl_xor(t, 8);
            ls[qi][r] = t;
        }

    // h1 publishes partials; h0 merges and writes out
    if (hh) {
        #pragma unroll
        for (int qi = 0; qi < 2; qi++)
            #pragma unroll
            for (int r = 0; r < 4; r++) {
                const int row = qi*16 + lq*4 + r;
                if (l16 == 0) { LM[pair][row] = mr[qi][r]; LL[pair][row] = ls[qi][r]; }
                #pragma unroll
                for (int d = 0; d < 4; d++)
                    LO[pair][row][d*16 + l16] = o[qi][d][r];
            }
    }
    __syncthreads();
    if (!hh) {
        #pragma unroll
        for (int qi = 0; qi < 2; qi++)
            #pragma unroll
            for (int r = 0; r < 4; r++) {
                const int row = qi*16 + lq*4 + r;
                const float m1 = LM[pair][row], l1 = LL[pair][row];
                const float m0 = mr[qi][r];
                const float M  = fmaxf(m0, m1);
                const float f0 = exp2f(m0 - M), f1 = exp2f(m1 - M);
                const float inv = 1.f / (ls[qi][r] * f0 + l1 * f1);
                const int srow = q0 + row;
                #pragma unroll
                for (int d = 0; d < 4; d++) {
                    float v = (o[qi][d][r] * f0 + LO[pair][row][d*16 + l16] * f1) * inv;
                    Oa[((size_t)b * NS + srow) * ND + h*64 + d*16 + l16] = (__bf16)v;
                }
            }
    }
}

extern "C" void kernel_launch(void* const* d_in, const int* in_sizes, int n_in,
                              void* d_out, int out_size, void* d_ws, size_t ws_size,
                              hipStream_t stream) {
    const float* x  = (const float*)d_in[0];
    const float* wq = (const float*)d_in[1];
    const float* wk = (const float*)d_in[2];
    const float* wv = (const float*)d_in[3];
    const float* wo = (const float*)d_in[4];
    char* ws = (char*)d_ws;

    __bf16* xb  = (__bf16*)(ws);                      // 16 MB  [M,K]
    __bf16* wqb = (__bf16*)(ws + (16ull << 20));      //  2 MB
    __bf16* wkb = (__bf16*)(ws + (18ull << 20));
    __bf16* wvb = (__bf16*)(ws + (20ull << 20));
    __bf16* wob = (__bf16*)(ws + (22ull << 20));
    __bf16* Qb  = (__bf16*)(ws + (24ull << 20));      // 16 MB [B,H,S,Dh]
    __bf16* Kb  = (__bf16*)(ws + (40ull << 20));      // 16 MB [B,H,S,Dh]
    __bf16* Vtb = (__bf16*)(ws + (56ull << 20));      // 16 MB [B,H,Dh,S]
    __bf16* Ab  = (__bf16*)(ws + (72ull << 20));      // 16 MB [B,S,D]
    float* out  = (float*)d_out;

    cast4<<<dim3(NM * ND / 1024), 256, 0, stream>>>(x,  xb,  NM * ND);
    cast4<<<dim3(ND * ND / 1024), 256, 0, stream>>>(wq, wqb, ND * ND);
    cast4<<<dim3(ND * ND / 1024), 256, 0, stream>>>(wk, wkb, ND * ND);
    cast4<<<dim3(ND * ND / 1024), 256, 0, stream>>>(wv, wvb, ND * ND);
    cast4<<<dim3(ND * ND / 1024), 256, 0, stream>>>(wo, wob, ND * ND);

    gemm128<0><<<dim3(NM/128, ND/128, 3), 256, 0, stream>>>(
        xb, wqb, wkb, wvb, Qb, Kb, Vtb, nullptr);

    attn_wv<<<dim3(2048), 256, 0, stream>>>(Qb, Kb, Vtb, Ab);

    gemm128<1><<<dim3(NM/128, ND/128), 256, 0, stream>>>(
        Ab, wob, nullptr, nullptr, nullptr, nullptr, nullptr, out);
}

// Round 9
// 251.400 us; speedup vs baseline: 1.1129x; 1.1129x over previous
//
#include <hip/hip_runtime.h>
#include <hip/hip_bf16.h>

typedef __bf16 bf16x8 __attribute__((ext_vector_type(8)));
typedef __bf16 bf16x4 __attribute__((ext_vector_type(4)));
typedef float f32x4 __attribute__((ext_vector_type(4)));

#define NB 4
#define NS 2048
#define ND 1024
#define NH 16
#define NDH 64
#define NM (NB*NS)   // 8192

#define MFMA(a,b,c) __builtin_amdgcn_mfma_f32_16x16x32_bf16((a),(b),(c),0,0,0)

__device__ __forceinline__ void gload16(const void* g, void* l) {
    __builtin_amdgcn_global_load_lds(
        (const __attribute__((address_space(1))) void*)(g),
        (__attribute__((address_space(3))) void*)(l),
        16, 0, 0);
}

// ---------------- cast fp32 -> bf16, vectorized ----------------
__global__ __launch_bounds__(256) void cast4(const float* __restrict__ in,
                                             __bf16* __restrict__ out, int n) {
    int i = (blockIdx.x * 256 + threadIdx.x) * 4;
    if (i >= n) return;
    float4 v = *(const float4*)(in + i);
    bf16x4 o;
    o[0] = (__bf16)v.x; o[1] = (__bf16)v.y; o[2] = (__bf16)v.z; o[3] = (__bf16)v.w;
    *(bf16x4*)(out + i) = o;
}

// ---------------- 128x128 GEMM, A[M,K] * W[N,K]^T ----------------
// MODE 0: z=0 -> Q [B,H,S,Dh] (scaled by 1/8*log2e), z=1 -> K, z=2 -> V^T [B,H,Dh,S]
// MODE 1: C fp32 row-major [M,N]
template<int MODE>
__global__ __launch_bounds__(256) void gemm128(
    const __bf16* __restrict__ A,
    const __bf16* __restrict__ W0, const __bf16* __restrict__ W1,
    const __bf16* __restrict__ W2,
    __bf16* __restrict__ O0, __bf16* __restrict__ O1, __bf16* __restrict__ O2,
    float* __restrict__ Cf)
{
    __shared__ alignas(16) __bf16 As[128*32];
    __shared__ alignas(16) __bf16 Bs[128*32];

    const int tid  = threadIdx.x;
    const int wave = tid >> 6, lane = tid & 63;
    const int l16  = lane & 15, lq = lane >> 4;
    const int bm = blockIdx.x * 128;
    const int bn = blockIdx.y * 128;
    const int z  = (MODE == 0) ? blockIdx.z : 0;
    const __bf16* __restrict__ Bw =
        (MODE == 0) ? ((z == 0) ? W0 : (z == 1) ? W1 : W2) : W0;

    const int wr = (wave >> 1) * 64;
    const int wc = (wave & 1) * 64;

    f32x4 acc[4][4];
    #pragma unroll
    for (int i = 0; i < 4; i++)
        #pragma unroll
        for (int j = 0; j < 4; j++)
            acc[i][j] = (f32x4){0.f, 0.f, 0.f, 0.f};

    const int ch0 = tid, ch1 = tid + 256;
    const int r0 = ch0 >> 2, c0 = (ch0 & 3) * 8;
    const int r1 = ch1 >> 2, c1 = (ch1 & 3) * 8;

    for (int k0 = 0; k0 < ND; k0 += 32) {
        __syncthreads();
        gload16(A  + (size_t)(bm + r0) * ND + k0 + c0, As + ch0 * 8);
        gload16(Bw + (size_t)(bn + r0) * ND + k0 + c0, Bs + ch0 * 8);
        gload16(A  + (size_t)(bm + r1) * ND + k0 + c1, As + ch1 * 8);
        gload16(Bw + (size_t)(bn + r1) * ND + k0 + c1, Bs + ch1 * 8);
        __syncthreads();

        bf16x8 af[4], bf[4];
        #pragma unroll
        for (int i = 0; i < 4; i++) {
            af[i] = *(const bf16x8*)(As + (wr + i*16 + l16) * 32 + lq * 8);
            bf[i] = *(const bf16x8*)(Bs + (wc + i*16 + l16) * 32 + lq * 8);
        }
        #pragma unroll
        for (int i = 0; i < 4; i++)
            #pragma unroll
            for (int j = 0; j < 4; j++)
                acc[i][j] = MFMA(af[i], bf[j], acc[i][j]);
    }

    #pragma unroll
    for (int i = 0; i < 4; i++) {
        #pragma unroll
        for (int j = 0; j < 4; j++) {
            #pragma unroll
            for (int r = 0; r < 4; r++) {
                int row = bm + wr + i*16 + lq*4 + r;   // m index (b*S + s)
                int col = bn + wc + j*16 + l16;        // n index (d_out)
                float v = acc[i][j][r];
                if (MODE == 1) {
                    Cf[(size_t)row * ND + col] = v;
                } else {
                    if (z == 0) v *= 0.1803368801111204f;  // 1/8 * log2(e)
                    int b = row >> 11, s = row & 2047;
                    int h = col >> 6,  dh = col & 63;
                    if (z < 2) {
                        __bf16* dst = (z == 0) ? O0 : O1;
                        dst[(((size_t)b*NH + h)*NS + s)*NDH + dh] = (__bf16)v;
                    } else {
                        O2[(((size_t)b*NH + h)*NDH + dh)*NS + s] = (__bf16)v;
                    }
                }
            }
        }
    }
}

// ------- causal flash attention: swapped-QK^T, wave-independent -------------
// Task = (bh, 32-row q-block j); 1024 blocks x 4 wave-tasks (round-7 layout).
// S computed as mfma(K,Q) so each lane owns ONE q-column (q = l16) with its
// 16 kv scores in-lane: row-max/row-sum = in-lane tree + 2 shfl_xor (vs 32
// bpermutes before). P goes through a per-wave swizzled LDS relayout to
// A-fragment form for PV. K/V addresses are running pointers (+= const) with
// immediate offsets. Scores in log2 units (scale folded into Q); defer-max.
__global__ __launch_bounds__(256, 2) void attn_sw(
    const __bf16* __restrict__ Q, const __bf16* __restrict__ K,
    const __bf16* __restrict__ Vt, __bf16* __restrict__ Oa)
{
    __shared__ alignas(16) __bf16 Ps[4][32*64];  // per-wave [q][kv], kv^((q&7)<<3)
    __shared__ float Fs[4][32];                  // per-wave fac / lsum broadcast

    const int tid  = threadIdx.x;
    const int wave = tid >> 6, lane = tid & 63;
    const int l16  = lane & 15, lq = lane >> 4;

    const int bid = blockIdx.x;                   // 0..1023
    const int bh  = (bid & 7) * 8 + ((bid >> 3) & 7);   // head group pinned/XCD
    const int jg  = bid >> 6;                     // 0..15
    const int j   = 63 - (jg * 4 + wave);         // q-block index 0..63
    const int q0  = j * 32;
    const int ntk = (j >> 1) + 1;                 // # of 64-wide kv tiles

    const int b = bh >> 4, h = bh & 15;
    const size_t qkb = (size_t)bh * NS * NDH;     // Q,K  [bh][s][dh]
    const size_t vbb = (size_t)bh * NDH * NS;     // Vt   [bh][dh][s]
    const int swq = (l16 & 7) << 3;               // P row swizzle (row = q)
    __bf16* Pw = Ps[wave];
    float*  Fw = Fs[wave];

    // Q fragments (B-operand): row = l16 -> q = qi*16+l16, k = lq*8
    bf16x8 qf[2][2];
    #pragma unroll
    for (int qi = 0; qi < 2; qi++) {
        const __bf16* qr = Q + qkb + (size_t)(q0 + qi*16 + l16) * NDH;
        qf[qi][0] = *(const bf16x8*)(qr + lq * 8);
        qf[qi][1] = *(const bf16x8*)(qr + 32 + lq * 8);
    }

    // o[qi][d]: row q = qi*16 + lq*4 + r, col = d*16 + l16
    f32x4 o[2][4];
    #pragma unroll
    for (int qi = 0; qi < 2; qi++)
        #pragma unroll
        for (int d = 0; d < 4; d++)
            o[qi][d] = (f32x4){0.f, 0.f, 0.f, 0.f};
    // softmax state: lane's q = qi*16 + l16 (replicated over lq)
    float mr[2]  = {-__builtin_inff(), -__builtin_inff()};
    float lsum[2] = {0.f, 0.f};

    // running pointers: K A-frag row = l16 (+16 per ni), k-chunk = lq*8
    const __bf16* kpt = K + qkb + (size_t)l16 * NDH + lq * 8;
    const __bf16* vp0 = Vt + vbb + (size_t)l16 * NS + lq * 8;
    const __bf16* vp1 = vp0 + 16 * NS;
    const __bf16* vp2 = vp0 + 32 * NS;
    const __bf16* vp3 = vp0 + 48 * NS;

    #pragma unroll 1
    for (int t = 0; t < ntk; ++t) {
        bf16x8 kf[4][2];
        #pragma unroll
        for (int ni = 0; ni < 4; ni++) {
            kf[ni][0] = *(const bf16x8*)(kpt + ni * 1024);
            kf[ni][1] = *(const bf16x8*)(kpt + ni * 1024 + 32);
        }
        bf16x8 vb[4][2];
        vb[0][0] = *(const bf16x8*)(vp0);      vb[0][1] = *(const bf16x8*)(vp0 + 32);
        vb[1][0] = *(const bf16x8*)(vp1);      vb[1][1] = *(const bf16x8*)(vp1 + 32);
        vb[2][0] = *(const bf16x8*)(vp2);      vb[2][1] = *(const bf16x8*)(vp2 + 32);
        vb[3][0] = *(const bf16x8*)(vp3);      vb[3][1] = *(const bf16x8*)(vp3 + 32);

        const bool diag = (t == ntk - 1);
        const int  dq   = q0 - t * 64;            // >= 0; used only at diag

        #pragma unroll
        for (int qi = 0; qi < 2; qi++) {
            // S[kv][q]: row = kv (in-lane: ni*16 + lq*4 + r), col = q = l16
            f32x4 s[4];
            __builtin_amdgcn_s_setprio(1);
            #pragma unroll
            for (int ni = 0; ni < 4; ni++) {
                if (diag && ni*16 > dq + qi*16 + 15) {   // fully-masked subtile
                    s[ni] = (f32x4){-__builtin_inff(), -__builtin_inff(),
                                    -__builtin_inff(), -__builtin_inff()};
                } else {
                    f32x4 z = (f32x4){0.f, 0.f, 0.f, 0.f};
                    z = MFMA(kf[ni][0], qf[qi][0], z);
                    z = MFMA(kf[ni][1], qf[qi][1], z);
                    s[ni] = z;
                }
            }
            __builtin_amdgcn_s_setprio(0);

            if (diag) {
                const int qrel = dq + qi*16 + l16;
                #pragma unroll
                for (int ni = 0; ni < 4; ni++)
                    #pragma unroll
                    for (int r = 0; r < 4; r++)
                        if (ni*16 + lq*4 + r > qrel) s[ni][r] = -__builtin_inff();
            }

            // row max for lane's q: in-lane tree + 2 cross-lane
            float m0 = fmaxf(fmaxf(s[0][0], s[0][1]), fmaxf(s[0][2], s[0][3]));
            float m1 = fmaxf(fmaxf(s[1][0], s[1][1]), fmaxf(s[1][2], s[1][3]));
            float m2 = fmaxf(fmaxf(s[2][0], s[2][1]), fmaxf(s[2][2], s[2][3]));
            float m3 = fmaxf(fmaxf(s[3][0], s[3][1]), fmaxf(s[3][2], s[3][3]));
            float tm = fmaxf(fmaxf(m0, m1), fmaxf(m2, m3));
            tm = fmaxf(tm, __shfl_xor(tm, 16));
            tm = fmaxf(tm, __shfl_xor(tm, 32));

            // defer-max rescale (rare): transport fac to o-layout via LDS
            if (__any(tm > mr[qi] + 8.f)) {
                float mnew = fmaxf(mr[qi], tm);
                float fac  = exp2f(mr[qi] - mnew);
                mr[qi] = mnew;
                lsum[qi] *= fac;
                if (lane < 16) Fw[qi*16 + lane] = fac;
                f32x4 fo = *(const f32x4*)&Fw[qi*16 + lq*4];
                #pragma unroll
                for (int d = 0; d < 4; d++) o[qi][d] *= fo;
            }

            // P = exp2(s - m); in-lane partial sum; write to swizzled LDS
            float psum = 0.f;
            __bf16* pr = Pw + (qi*16 + l16) * 64;
            #pragma unroll
            for (int ni = 0; ni < 4; ni++)
                #pragma unroll
                for (int r = 0; r < 4; r++) {
                    float pv = exp2f(s[ni][r] - mr[qi]);
                    psum += pv;
                    pr[(ni*16 + lq*4 + r) ^ swq] = (__bf16)pv;
                }
            psum += __shfl_xor(psum, 16);
            psum += __shfl_xor(psum, 32);
            lsum[qi] += psum;

            // PV: A = P rows (q = l16-based, same row as written), B = V^T rows
            bf16x8 pa0 = *(const bf16x8*)(pr + ((lq*8) ^ swq));
            bf16x8 pa1 = *(const bf16x8*)(pr + ((32 + lq*8) ^ swq));
            __builtin_amdgcn_s_setprio(1);
            #pragma unroll
            for (int d = 0; d < 4; d++) {
                o[qi][d] = MFMA(pa0, vb[d][0], o[qi][d]);
                o[qi][d] = MFMA(pa1, vb[d][1], o[qi][d]);
            }
            __builtin_amdgcn_s_setprio(0);
        }

        kpt += 64 * NDH;   // next 64 kv rows
        vp0 += 64; vp1 += 64; vp2 += 64; vp3 += 64;
    }

    // transport lsum (per-lane q = l16) to o-layout (q = lq*4+r) and store
    if (lane < 16) { Fw[lane] = lsum[0]; Fw[16 + lane] = lsum[1]; }
    #pragma unroll
    for (int qi = 0; qi < 2; qi++) {
        f32x4 lv = *(const f32x4*)&Fw[qi*16 + lq*4];
        #pragma unroll
        for (int r = 0; r < 4; r++) {
            float inv = 1.f / lv[r];
            int srow = q0 + qi*16 + lq*4 + r;
            #pragma unroll
            for (int d = 0; d < 4; d++)
                Oa[((size_t)b * NS + srow) * ND + h*64 + d*16 + l16] =
                    (__bf16)(o[qi][d][r] * inv);
        }
    }
}

extern "C" void kernel_launch(void* const* d_in, const int* in_sizes, int n_in,
                              void* d_out, int out_size, void* d_ws, size_t ws_size,
                              hipStream_t stream) {
    const float* x  = (const float*)d_in[0];
    const float* wq = (const float*)d_in[1];
    const float* wk = (const float*)d_in[2];
    const float* wv = (const float*)d_in[3];
    const float* wo = (const float*)d_in[4];
    char* ws = (char*)d_ws;

    __bf16* xb  = (__bf16*)(ws);                      // 16 MB  [M,K]
    __bf16* wqb = (__bf16*)(ws + (16ull << 20));      //  2 MB
    __bf16* wkb = (__bf16*)(ws + (18ull << 20));
    __bf16* wvb = (__bf16*)(ws + (20ull << 20));
    __bf16* wob = (__bf16*)(ws + (22ull << 20));
    __bf16* Qb  = (__bf16*)(ws + (24ull << 20));      // 16 MB [B,H,S,Dh]
    __bf16* Kb  = (__bf16*)(ws + (40ull << 20));      // 16 MB [B,H,S,Dh]
    __bf16* Vtb = (__bf16*)(ws + (56ull << 20));      // 16 MB [B,H,Dh,S]
    __bf16* Ab  = (__bf16*)(ws + (72ull << 20));      // 16 MB [B,S,D]
    float* out  = (float*)d_out;

    cast4<<<dim3(NM * ND / 1024), 256, 0, stream>>>(x,  xb,  NM * ND);
    cast4<<<dim3(ND * ND / 1024), 256, 0, stream>>>(wq, wqb, ND * ND);
    cast4<<<dim3(ND * ND / 1024), 256, 0, stream>>>(wk, wkb, ND * ND);
    cast4<<<dim3(ND * ND / 1024), 256, 0, stream>>>(wv, wvb, ND * ND);
    cast4<<<dim3(ND * ND / 1024), 256, 0, stream>>>(wo, wob, ND * ND);

    gemm128<0><<<dim3(NM/128, ND/128, 3), 256, 0, stream>>>(
        xb, wqb, wkb, wvb, Qb, Kb, Vtb, nullptr);

    attn_sw<<<dim3(1024), 256, 0, stream>>>(Qb, Kb, Vtb, Ab);

    gemm128<1><<<dim3(NM/128, ND/128), 256, 0, stream>>>(
        Ab, wob, nullptr, nullptr, nullptr, nullptr, nullptr, out);
}